// Round 16
// baseline (210.521 us; speedup 1.0000x reference)
//
#include <hip/hip_runtime.h>
#include <hip/hip_bf16.h>

#define B_ 4
#define N_ 512
#define F_ 64
#define H_ 64
#define K_ 64
#define BN_ (B_*N_)
#define EPS_ 1e-14f
#define LOG2E_ 1.4426950408889634f
#define LN2_   0.6931471805599453f

typedef __attribute__((ext_vector_type(8))) short short8;
typedef __attribute__((ext_vector_type(4))) float f32x4;
typedef __attribute__((ext_vector_type(2))) float f32x2;

__device__ __forceinline__ unsigned short f2bf(float f) {
    __hip_bfloat16 b = __float2bfloat16(f);     // hw v_cvt path
    return __builtin_bit_cast(unsigned short, b);
}
__device__ __forceinline__ float lane_bcast(float v, int lane) {
    return __int_as_float(__builtin_amdgcn_readlane(__float_as_int(v), lane));
}
__device__ __forceinline__ float rcpf(float x) { return __builtin_amdgcn_rcpf(x); }
__device__ __forceinline__ float exp2f_(float x) { return __builtin_amdgcn_exp2f(x); }
__device__ __forceinline__ float fast_silu(float x) {          // real-unit silu
    return x * rcpf(1.0f + exp2f_(-LOG2E_ * x));
}

// ws (floats): PJ2[BN][64][2] ({ew',es'} pre-scaled) | PI_EW'[BN*64] | PI_ES'[BN*64] | PJSA[BN] | PISA[BN]
// ew' = ew * 2*log2e ; es' = es * log2e  (exp-arg scalings folded in)
#define W_PJ2  0
#define W_PIEW (BN_*128)
#define W_PIES (BN_*128 + BN_*64)
#define W_PJSA (BN_*128 + 2*BN_*64)
#define W_PISA (BN_*128 + 2*BN_*64 + BN_)

__global__ __launch_bounds__(64) void proj_kernel(
    const float* __restrict__ h, const float* __restrict__ W_ew,
    const float* __restrict__ W_sa, const float* __restrict__ W_es,
    float* __restrict__ ws)
{
    const int node = blockIdx.x;
    const int t = threadIdx.x;
    __shared__ float sh[F_];
    sh[t] = h[node*F_ + t];
    __syncthreads();
    float a_jew=0.f, a_iew=0.f, a_jes=0.f, a_ies=0.f, a_jsa=0.f, a_isa=0.f;
    #pragma unroll 8
    for (int f = 0; f < F_; ++f) {
        const float hv = sh[f];
        a_jew += hv * W_ew[f*K_ + t];          // h @ W_ew[:F]
        a_iew += hv * W_ew[(F_+f)*K_ + t];     // h @ W_ew[F:]
        a_jes += hv * W_es[(1+f)*H_ + t];      // h @ W_es[1:][:F]
        a_ies += hv * W_es[(1+F_+f)*H_ + t];   // h @ W_es[1:][F:]
        a_jsa += hv * W_sa[f];
        a_isa += hv * W_sa[F_+f];
    }
    ws[W_PJ2 + (size_t)node*128 + t*2 + 0] = a_jew * (2.0f*LOG2E_);
    ws[W_PJ2 + (size_t)node*128 + t*2 + 1] = a_jes * LOG2E_;
    ws[W_PIEW + node*K_ + t] = a_iew * (2.0f*LOG2E_);
    ws[W_PIES + node*H_ + t] = a_ies * LOG2E_;
    if (t == 0) { ws[W_PJSA + node] = a_jsa; ws[W_PISA + node] = a_isa; }
}

__global__ __launch_bounds__(256) void main_kernel(
    const float* __restrict__ h, const float* __restrict__ x,
    const float* __restrict__ b_ew, const float* __restrict__ b_es,
    const float* __restrict__ W_es, const float* __restrict__ W_c1,
    const float* __restrict__ b_c1, const float* __restrict__ W_c2,
    const float* __restrict__ b_c2, const float* __restrict__ W_n,
    const float* __restrict__ b_n,
    const float* __restrict__ ws, float* __restrict__ out)
{
    const int bi   = blockIdx.x;          // b*N + i
    const int b    = bi >> 9;
    const int base = b * N_;
    const int tid  = threadIdx.x;
    const int w    = tid >> 6;            // wave 0..3
    const int lane = tid & 63;
    const int quad = lane >> 4;
    const int l16  = lane & 15;

    __shared__ unsigned short he_buf[4][32][72];  // bf16 he' subtile (log2e-units)
    __shared__ float sdA[4][64][4];       // {v0,v1,v2,filt} per j
    __shared__ float coord_buf[4][64];
    __shared__ float s_att[3][4][64];
    __shared__ float s_hea[4][64];
    __shared__ float s_misc[4][4];        // per wave: sum_e, xa0, xa1, xa2
    __shared__ float s_concat[192];
    __shared__ float s_hnew[4][64];

    const float pi_ew_t = ws[W_PIEW + bi*K_ + lane] + b_ew[lane]*(2.0f*LOG2E_);
    const float pi_es_t = ws[W_PIES + bi*H_ + lane] + b_es[lane]*LOG2E_;
    const float pisa    = ws[W_PISA + bi];
    const float xi0 = x[bi*3+0], xi1 = x[bi*3+1], xi2 = x[bi*3+2];
    const float wes0_t = W_es[lane]*LOG2E_;
    const float bc2    = b_c2[0];

    float bc1v[4], wc2v[4];
    #pragma unroll
    for (int nt = 0; nt < 4; ++nt) {
        bc1v[nt] = b_c1[nt*16 + l16];
        wc2v[nt] = W_c2[nt*16 + l16];
    }

    // W_c1 B-fragments, scaled by ln2 to compensate he' = he*log2e
    short8 Bf[4][2];
    #pragma unroll
    for (int nt = 0; nt < 4; ++nt)
        #pragma unroll
        for (int kc = 0; kc < 2; ++kc)
            #pragma unroll
            for (int r = 0; r < 8; ++r) {
                const int k = kc*32 + quad*8 + r;
                Bf[nt][kc][r] = (short)f2bf(W_c1[k*H_ + nt*16 + l16] * LN2_);
            }

    float att0=0.f, att1=0.f, att2=0.f, hea=0.f, sume=0.f;
    float xa0=0.f, xa1=0.f, xa2=0.f;

    for (int c = 0; c < 2; ++c) {
        const int j0 = (w*2 + c) * 64;

        // ---- phase A: per-j scalars (lane = jj over 64) ----
        float esem, d0, d1, d2;
        {
            const int gj = base + j0 + lane;
            d0 = x[gj*3+0] - xi0;
            d1 = x[gj*3+1] - xi1;
            d2 = x[gj*3+2] - xi2;
            const float d2s = fmaf(d0,d0, fmaf(d1,d1, d2*d2));
            const float nrm = sqrtf(d2s + EPS_);
            const float e   = exp2f_(nrm * LOG2E_);
            sume += e;
            const float filt = rcpf(nrm + 0.1f);
            const float inv  = rcpf(fmaf(nrm, nrm, EPS_));
            const float sv   = ws[W_PJSA + gj] + pisa;
            const float sem  = (sv >= 0.f) ? sv : 0.01f*sv;
            esem = e * sem * LN2_;    // ln2 folded (compensates he' scaling)
            f32x4 p0 = { d0*inv, d1*inv, d2*inv, filt };
            *(f32x4*)&sdA[w][lane][0] = p0;
        }

        // two 32-j subchunks: phase B fills he subtile, phase C MFMAs it
        #pragma unroll
        for (int s = 0; s < 2; ++s) {
            const int sj = s*32;
            const float* pjp = ws + W_PJ2 + (size_t)(base + j0 + sj)*128 + lane*2;
            #pragma unroll 8
            for (int jj = 0; jj < 32; ++jj, pjp += 128) {
                const f32x2 pj = *(const f32x2*)pjp;
                const f32x4 p0 = *(const f32x4*)&sdA[w][sj + jj][0];   // broadcast
                const float esem_s = lane_bcast(esem, sj + jj);
                // silu in log2e-units: pre' = log2e*pre; he' = pre'*sigmoid(pre)
                const float pre = fmaf(p0.w, wes0_t, pj.y + pi_es_t);
                const float he  = pre * rcpf(1.0f + exp2f_(-pre));
                hea = fmaf(esem_s, he, hea);
                he_buf[w][jj][lane] = f2bf(he);
                // tanh: arg already *2log2e -> t = 2^arg
                const float t = exp2f_(pj.x + pi_ew_t);
                const float ewt = fmaf(-2.0f, rcpf(t + 1.0f), 1.0f);
                att0 = fmaf(ewt, p0.x, att0);
                att1 = fmaf(ewt, p0.y, att1);
                att2 = fmaf(ewt, p0.z, att2);
            }

            // ---- phase C: coord MLP via MFMA on the 32-row subtile ----
            #pragma unroll
            for (int mt = 0; mt < 2; ++mt) {
                const short8 a0 = *(const short8*)&he_buf[w][mt*16 + l16][quad*8];
                const short8 a1 = *(const short8*)&he_buf[w][mt*16 + l16][32 + quad*8];
                float rs0=0.f, rs1=0.f, rs2=0.f, rs3=0.f;
                #pragma unroll
                for (int nt = 0; nt < 4; ++nt) {
                    f32x4 acc = {0.f, 0.f, 0.f, 0.f};
                    acc = __builtin_amdgcn_mfma_f32_16x16x32_bf16(a0, Bf[nt][0], acc, 0, 0, 0);
                    acc = __builtin_amdgcn_mfma_f32_16x16x32_bf16(a1, Bf[nt][1], acc, 0, 0, 0);
                    rs0 += fast_silu(acc[0] + bc1v[nt]) * wc2v[nt];
                    rs1 += fast_silu(acc[1] + bc1v[nt]) * wc2v[nt];
                    rs2 += fast_silu(acc[2] + bc1v[nt]) * wc2v[nt];
                    rs3 += fast_silu(acc[3] + bc1v[nt]) * wc2v[nt];
                }
                #pragma unroll
                for (int m = 1; m <= 8; m <<= 1) {      // reduce over cols (l16)
                    rs0 += __shfl_xor(rs0, m, 64);
                    rs1 += __shfl_xor(rs1, m, 64);
                    rs2 += __shfl_xor(rs2, m, 64);
                    rs3 += __shfl_xor(rs3, m, 64);
                }
                if (l16 == 0) {
                    f32x4 cv = { rs0 + bc2, rs1 + bc2, rs2 + bc2, rs3 + bc2 };
                    *(f32x4*)&coord_buf[w][sj + mt*16 + quad*4] = cv;
                }
            }
        }

        // ---- phase D: xa += d * coord (lane = jj over 64) ----
        {
            const float cj = coord_buf[w][lane];
            xa0 = fmaf(d0, cj, xa0);
            xa1 = fmaf(d1, cj, xa1);
            xa2 = fmaf(d2, cj, xa2);
        }
    }

    // wave-level reduce of j-lane partials
    #pragma unroll
    for (int m = 32; m >= 1; m >>= 1) {
        sume += __shfl_xor(sume, m, 64);
        xa0  += __shfl_xor(xa0,  m, 64);
        xa1  += __shfl_xor(xa1,  m, 64);
        xa2  += __shfl_xor(xa2,  m, 64);
    }
    s_att[0][w][lane] = att0;
    s_att[1][w][lane] = att1;
    s_att[2][w][lane] = att2;
    s_hea[w][lane]    = hea;
    if (lane == 0) {
        s_misc[w][0] = sume; s_misc[w][1] = xa0; s_misc[w][2] = xa1; s_misc[w][3] = xa2;
    }
    __syncthreads();

    if (w == 0) {
        const float a0 = s_att[0][0][lane]+s_att[0][1][lane]+s_att[0][2][lane]+s_att[0][3][lane];
        const float a1 = s_att[1][0][lane]+s_att[1][1][lane]+s_att[1][2][lane]+s_att[1][3][lane];
        const float a2 = s_att[2][0][lane]+s_att[2][1][lane]+s_att[2][2][lane]+s_att[2][3][lane];
        const float hg = s_hea[0][lane]+s_hea[1][lane]+s_hea[2][lane]+s_hea[3][lane];
        const float se = s_misc[0][0]+s_misc[1][0]+s_misc[2][0]+s_misc[3][0];
        const float attn = sqrtf(fmaf(a0,a0, fmaf(a1,a1, a2*a2)) + EPS_);
        s_concat[lane]       = h[bi*F_ + lane];
        s_concat[64 + lane]  = hg * rcpf(se);
        s_concat[128 + lane] = attn;
    }
    if (tid < 3) {
        const float xat = s_misc[0][1+tid]+s_misc[1][1+tid]+s_misc[2][1+tid]+s_misc[3][1+tid];
        out[(size_t)BN_*H_ + bi*3 + tid] = x[bi*3+tid] + xat;       // x_new
    }
    __syncthreads();

    // output GEMV split across 4 waves (48 rows each)
    {
        float acc = 0.f;
        const int m0 = w * 48;
        #pragma unroll 8
        for (int m = m0; m < m0 + 48; ++m)
            acc = fmaf(s_concat[m], W_n[m*H_ + lane], acc);
        s_hnew[w][lane] = acc;
    }
    __syncthreads();
    if (w == 0) {
        out[bi*H_ + lane] = s_hnew[0][lane] + s_hnew[1][lane]
                          + s_hnew[2][lane] + s_hnew[3][lane] + b_n[lane];  // h_new
    }
}

extern "C" void kernel_launch(void* const* d_in, const int* in_sizes, int n_in,
                              void* d_out, int out_size, void* d_ws, size_t ws_size,
                              hipStream_t stream) {
    (void)in_sizes; (void)n_in; (void)out_size; (void)ws_size;
    const float* h    = (const float*)d_in[0];
    const float* x    = (const float*)d_in[1];
    const float* W_ew = (const float*)d_in[2];
    const float* b_ew = (const float*)d_in[3];
    const float* W_sa = (const float*)d_in[4];
    const float* W_es = (const float*)d_in[5];
    const float* b_es = (const float*)d_in[6];
    const float* W_c1 = (const float*)d_in[7];
    const float* b_c1 = (const float*)d_in[8];
    const float* W_c2 = (const float*)d_in[9];
    const float* b_c2 = (const float*)d_in[10];
    const float* W_n  = (const float*)d_in[11];
    const float* b_n  = (const float*)d_in[12];
    float* out = (float*)d_out;
    float* ws  = (float*)d_ws;

    proj_kernel<<<dim3(BN_), dim3(64), 0, stream>>>(h, W_ew, W_sa, W_es, ws);
    main_kernel<<<dim3(BN_), dim3(256), 0, stream>>>(h, x, b_ew, b_es, W_es, W_c1,
                                                     b_c1, W_c2, b_c2, W_n, b_n, ws, out);
}

// Round 17
// 162.414 us; speedup vs baseline: 1.2962x; 1.2962x over previous
//
#include <hip/hip_runtime.h>

#define B_ 4
#define N_ 512
#define F_ 64
#define H_ 64
#define K_ 64
#define BN_ (B_*N_)
#define EPS_ 1e-14f
#define LOG2E_ 1.4426950408889634f
#define LN2_   0.6931471805599453f

typedef __attribute__((ext_vector_type(8))) short short8;
typedef __attribute__((ext_vector_type(4))) float f32x4;
typedef __attribute__((ext_vector_type(2))) float f32x2;

__device__ __forceinline__ unsigned short f2bf(float f) {
    const unsigned u = __float_as_uint(f);
    return (unsigned short)((u + 0x7FFFu + ((u >> 16) & 1u)) >> 16);
}
__device__ __forceinline__ float lane_bcast(float v, int lane) {
    return __int_as_float(__builtin_amdgcn_readlane(__float_as_int(v), lane));
}
__device__ __forceinline__ float rcpf(float x) { return __builtin_amdgcn_rcpf(x); }
__device__ __forceinline__ float exp2f_(float x) { return __builtin_amdgcn_exp2f(x); }
__device__ __forceinline__ float fast_silu(float x) {          // real-unit silu (phase C)
    return x * rcpf(1.0f + exp2f_(-LOG2E_ * x));
}

// ws (floats): PJ2[BN][64][2] ({ew',es'} pre-scaled) | PI_EW'[BN*64] | PI_ES'[BN*64] | PJSA[BN] | PISA[BN]
// ew' = ew * 2*log2e ; es' = es * log2e
#define W_PJ2  0
#define W_PIEW (BN_*128)
#define W_PIES (BN_*128 + BN_*64)
#define W_PJSA (BN_*128 + 2*BN_*64)
#define W_PISA (BN_*128 + 2*BN_*64 + BN_)

__global__ __launch_bounds__(64) void proj_kernel(
    const float* __restrict__ h, const float* __restrict__ W_ew,
    const float* __restrict__ W_sa, const float* __restrict__ W_es,
    float* __restrict__ ws)
{
    const int node = blockIdx.x;
    const int t = threadIdx.x;
    __shared__ float sh[F_];
    sh[t] = h[node*F_ + t];
    __syncthreads();
    float a_jew=0.f, a_iew=0.f, a_jes=0.f, a_ies=0.f, a_jsa=0.f, a_isa=0.f;
    #pragma unroll 8
    for (int f = 0; f < F_; ++f) {
        const float hv = sh[f];
        a_jew += hv * W_ew[f*K_ + t];          // h @ W_ew[:F]
        a_iew += hv * W_ew[(F_+f)*K_ + t];     // h @ W_ew[F:]
        a_jes += hv * W_es[(1+f)*H_ + t];      // h @ W_es[1:][:F]
        a_ies += hv * W_es[(1+F_+f)*H_ + t];   // h @ W_es[1:][F:]
        a_jsa += hv * W_sa[f];
        a_isa += hv * W_sa[F_+f];
    }
    ws[W_PJ2 + (size_t)node*128 + t*2 + 0] = a_jew * (2.0f*LOG2E_);
    ws[W_PJ2 + (size_t)node*128 + t*2 + 1] = a_jes * LOG2E_;
    ws[W_PIEW + node*K_ + t] = a_iew * (2.0f*LOG2E_);
    ws[W_PIES + node*H_ + t] = a_ies * LOG2E_;
    if (t == 0) { ws[W_PJSA + node] = a_jsa; ws[W_PISA + node] = a_isa; }
}

__global__ __launch_bounds__(256, 4) void main_kernel(
    const float* __restrict__ h, const float* __restrict__ x,
    const float* __restrict__ b_ew, const float* __restrict__ b_es,
    const float* __restrict__ W_es, const float* __restrict__ W_c1,
    const float* __restrict__ b_c1, const float* __restrict__ W_c2,
    const float* __restrict__ b_c2, const float* __restrict__ W_n,
    const float* __restrict__ b_n,
    const float* __restrict__ ws, float* __restrict__ out)
{
    const int bi   = blockIdx.x;          // b*N + i
    const int b    = bi >> 9;
    const int base = b * N_;
    const int tid  = threadIdx.x;
    const int w    = tid >> 6;            // wave 0..3
    const int lane = tid & 63;
    const int quad = lane >> 4;
    const int l16  = lane & 15;

    __shared__ unsigned short he_buf[4][32][72];  // bf16 he' subtile (log2e-units)
    __shared__ float sdA[4][64][4];       // {v0,v1,v2,filt} per j
    __shared__ float coord_buf[4][64];
    __shared__ float s_att[3][4][64];
    __shared__ float s_hea[4][64];
    __shared__ float s_misc[4][4];        // per wave: sum_e, xa0, xa1, xa2
    __shared__ float s_concat[192];
    __shared__ float s_hnew[4][64];

    const float pi_ew_t = ws[W_PIEW + bi*K_ + lane] + b_ew[lane]*(2.0f*LOG2E_);
    const float pi_es_t = ws[W_PIES + bi*H_ + lane] + b_es[lane]*LOG2E_;
    const float pisa    = ws[W_PISA + bi];
    const float xi0 = x[bi*3+0], xi1 = x[bi*3+1], xi2 = x[bi*3+2];
    const float wes0_t = W_es[lane]*LOG2E_;
    const float bc2    = b_c2[0];

    float bc1v[4], wc2v[4];
    #pragma unroll
    for (int nt = 0; nt < 4; ++nt) {
        bc1v[nt] = b_c1[nt*16 + l16];
        wc2v[nt] = W_c2[nt*16 + l16];
    }

    // W_c1 B-fragments scaled by ln2 (compensates he' = he*log2e)
    short8 Bf[4][2];
    #pragma unroll
    for (int nt = 0; nt < 4; ++nt)
        #pragma unroll
        for (int kc = 0; kc < 2; ++kc)
            #pragma unroll
            for (int r = 0; r < 8; ++r) {
                const int k = kc*32 + quad*8 + r;
                Bf[nt][kc][r] = (short)f2bf(W_c1[k*H_ + nt*16 + l16] * LN2_);
            }

    float att0=0.f, att1=0.f, att2=0.f, hea=0.f, sume=0.f;
    float xa0=0.f, xa1=0.f, xa2=0.f;

    for (int c = 0; c < 2; ++c) {
        const int j0 = (w*2 + c) * 64;

        // ---- phase A: per-j scalars (lane = jj over 64) ----
        float esem, d0, d1, d2;
        {
            const int gj = base + j0 + lane;
            d0 = x[gj*3+0] - xi0;
            d1 = x[gj*3+1] - xi1;
            d2 = x[gj*3+2] - xi2;
            const float d2s = fmaf(d0,d0, fmaf(d1,d1, d2*d2));
            const float nrm = sqrtf(d2s + EPS_);
            const float e   = exp2f_(nrm * LOG2E_);
            sume += e;
            const float filt = rcpf(nrm + 0.1f);
            const float inv  = rcpf(fmaf(nrm, nrm, EPS_));
            const float sv   = ws[W_PJSA + gj] + pisa;
            const float sem  = (sv >= 0.f) ? sv : 0.01f*sv;
            esem = e * sem * LN2_;    // ln2 folded (compensates he' scaling)
            f32x4 p0 = { d0*inv, d1*inv, d2*inv, filt };
            *(f32x4*)&sdA[w][lane][0] = p0;
        }

        // two 32-j subchunks: phase B fills he subtile, phase C MFMAs it
        #pragma unroll
        for (int s = 0; s < 2; ++s) {
            const int sj = s*32;
            #pragma unroll 4
            for (int jj = 0; jj < 32; ++jj) {
                const int gj = base + j0 + sj + jj;
                const f32x2 pj = *(const f32x2*)&ws[W_PJ2 + (size_t)gj*128 + lane*2];
                const f32x4 p0 = *(const f32x4*)&sdA[w][sj + jj][0];   // broadcast
                const float esem_s = lane_bcast(esem, sj + jj);
                // silu in log2e-units: pre' already scaled; he' = pre'*sigmoid(pre)
                const float pre = fmaf(p0.w, wes0_t, pj.y + pi_es_t);
                const float he  = pre * rcpf(1.0f + exp2f_(-pre));
                hea = fmaf(esem_s, he, hea);
                he_buf[w][jj][lane] = f2bf(he);
                // tanh: stored arg already *2log2e -> t = 2^arg
                const float t = exp2f_(pj.x + pi_ew_t);
                const float ewt = fmaf(-2.0f, rcpf(t + 1.0f), 1.0f);
                att0 = fmaf(ewt, p0.x, att0);
                att1 = fmaf(ewt, p0.y, att1);
                att2 = fmaf(ewt, p0.z, att2);
            }

            // ---- phase C: coord MLP via MFMA on the 32-row subtile ----
            #pragma unroll
            for (int mt = 0; mt < 2; ++mt) {
                const short8 a0 = *(const short8*)&he_buf[w][mt*16 + l16][quad*8];
                const short8 a1 = *(const short8*)&he_buf[w][mt*16 + l16][32 + quad*8];
                float rs0=0.f, rs1=0.f, rs2=0.f, rs3=0.f;
                #pragma unroll
                for (int nt = 0; nt < 4; ++nt) {
                    f32x4 acc = {0.f, 0.f, 0.f, 0.f};
                    acc = __builtin_amdgcn_mfma_f32_16x16x32_bf16(a0, Bf[nt][0], acc, 0, 0, 0);
                    acc = __builtin_amdgcn_mfma_f32_16x16x32_bf16(a1, Bf[nt][1], acc, 0, 0, 0);
                    rs0 += fast_silu(acc[0] + bc1v[nt]) * wc2v[nt];
                    rs1 += fast_silu(acc[1] + bc1v[nt]) * wc2v[nt];
                    rs2 += fast_silu(acc[2] + bc1v[nt]) * wc2v[nt];
                    rs3 += fast_silu(acc[3] + bc1v[nt]) * wc2v[nt];
                }
                #pragma unroll
                for (int m = 1; m <= 8; m <<= 1) {      // reduce over cols (l16)
                    rs0 += __shfl_xor(rs0, m, 64);
                    rs1 += __shfl_xor(rs1, m, 64);
                    rs2 += __shfl_xor(rs2, m, 64);
                    rs3 += __shfl_xor(rs3, m, 64);
                }
                if (l16 == 0) {
                    f32x4 cv = { rs0 + bc2, rs1 + bc2, rs2 + bc2, rs3 + bc2 };
                    *(f32x4*)&coord_buf[w][sj + mt*16 + quad*4] = cv;
                }
            }
        }

        // ---- phase D: xa += d * coord (lane = jj over 64) ----
        {
            const float cj = coord_buf[w][lane];
            xa0 = fmaf(d0, cj, xa0);
            xa1 = fmaf(d1, cj, xa1);
            xa2 = fmaf(d2, cj, xa2);
        }
    }

    // wave-level reduce of j-lane partials
    #pragma unroll
    for (int m = 32; m >= 1; m >>= 1) {
        sume += __shfl_xor(sume, m, 64);
        xa0  += __shfl_xor(xa0,  m, 64);
        xa1  += __shfl_xor(xa1,  m, 64);
        xa2  += __shfl_xor(xa2,  m, 64);
    }
    s_att[0][w][lane] = att0;
    s_att[1][w][lane] = att1;
    s_att[2][w][lane] = att2;
    s_hea[w][lane]    = hea;
    if (lane == 0) {
        s_misc[w][0] = sume; s_misc[w][1] = xa0; s_misc[w][2] = xa1; s_misc[w][3] = xa2;
    }
    __syncthreads();

    if (w == 0) {
        const float a0 = s_att[0][0][lane]+s_att[0][1][lane]+s_att[0][2][lane]+s_att[0][3][lane];
        const float a1 = s_att[1][0][lane]+s_att[1][1][lane]+s_att[1][2][lane]+s_att[1][3][lane];
        const float a2 = s_att[2][0][lane]+s_att[2][1][lane]+s_att[2][2][lane]+s_att[2][3][lane];
        const float hg = s_hea[0][lane]+s_hea[1][lane]+s_hea[2][lane]+s_hea[3][lane];
        const float se = s_misc[0][0]+s_misc[1][0]+s_misc[2][0]+s_misc[3][0];
        const float attn = sqrtf(fmaf(a0,a0, fmaf(a1,a1, a2*a2)) + EPS_);
        s_concat[lane]       = h[bi*F_ + lane];
        s_concat[64 + lane]  = hg * rcpf(se);
        s_concat[128 + lane] = attn;
    }
    if (tid < 3) {
        const float xat = s_misc[0][1+tid]+s_misc[1][1+tid]+s_misc[2][1+tid]+s_misc[3][1+tid];
        out[(size_t)BN_*H_ + bi*3 + tid] = x[bi*3+tid] + xat;       // x_new
    }
    __syncthreads();

    // output GEMV split across 4 waves (48 rows each)
    {
        float acc = 0.f;
        const int m0 = w * 48;
        #pragma unroll 8
        for (int m = m0; m < m0 + 48; ++m)
            acc = fmaf(s_concat[m], W_n[m*H_ + lane], acc);
        s_hnew[w][lane] = acc;
    }
    __syncthreads();
    if (w == 0) {
        out[bi*H_ + lane] = s_hnew[0][lane] + s_hnew[1][lane]
                          + s_hnew[2][lane] + s_hnew[3][lane] + b_n[lane];  // h_new
    }
}

extern "C" void kernel_launch(void* const* d_in, const int* in_sizes, int n_in,
                              void* d_out, int out_size, void* d_ws, size_t ws_size,
                              hipStream_t stream) {
    (void)in_sizes; (void)n_in; (void)out_size; (void)ws_size;
    const float* h    = (const float*)d_in[0];
    const float* x    = (const float*)d_in[1];
    const float* W_ew = (const float*)d_in[2];
    const float* b_ew = (const float*)d_in[3];
    const float* W_sa = (const float*)d_in[4];
    const float* W_es = (const float*)d_in[5];
    const float* b_es = (const float*)d_in[6];
    const float* W_c1 = (const float*)d_in[7];
    const float* b_c1 = (const float*)d_in[8];
    const float* W_c2 = (const float*)d_in[9];
    const float* b_c2 = (const float*)d_in[10];
    const float* W_n  = (const float*)d_in[11];
    const float* b_n  = (const float*)d_in[12];
    float* out = (float*)d_out;
    float* ws  = (float*)d_ws;

    proj_kernel<<<dim3(BN_), dim3(64), 0, stream>>>(h, W_ew, W_sa, W_es, ws);
    main_kernel<<<dim3(BN_), dim3(256), 0, stream>>>(h, x, b_ew, b_es, W_es, W_c1,
                                                     b_c1, W_c2, b_c2, W_n, b_n, ws, out);
}